// Round 21
// baseline (345.006 us; speedup 1.0000x reference)
//
#include <hip/hip_runtime.h>
#include <hip/hip_bf16.h>

#define B_ 4
#define T_ 2048
#define C_ 768
#define H_ 12
#define D_ 64
#define QS_ 2304   // packed qkv row stride

typedef __attribute__((ext_vector_type(8))) short short8;
typedef __attribute__((ext_vector_type(4))) short short4v;
typedef __attribute__((ext_vector_type(4))) float f32x4;

__device__ __forceinline__ unsigned short f2bf(float f) {
    __hip_bfloat16 h = __float2bfloat16(f);
    return *reinterpret_cast<unsigned short*>(&h);
}

__device__ __forceinline__ float bf2f(unsigned short u) {
    return __bfloat162float(*reinterpret_cast<const __hip_bfloat16*>(&u));
}

__device__ __forceinline__ unsigned cvt_pk_bf16(float lo, float hi) {
    unsigned r;
    asm("v_cvt_pk_bf16_f32 %0, %1, %2" : "=v"(r) : "v"(lo), "v"(hi));
    return r;
}

__device__ __forceinline__ void gl_lds16(const void* g, void* l) {
    __builtin_amdgcn_global_load_lds((const __attribute__((address_space(1))) unsigned int*)g,
                                     (__attribute__((address_space(3))) unsigned int*)l,
                                     16, 0, 0);
}

// ---------------- fused prep: transposes + bias concat + GEMV(c2,cb) + LN1 ------------
__device__ __forceinline__ void transpose_dev(const float* __restrict__ W,
                                              unsigned short* __restrict__ Wt,
                                              int K, int N, int bx, int by,
                                              float (*t)[65]) {
    int n0 = bx * 64, k0 = by * 64;
    int r = threadIdx.x >> 4, c4 = (threadIdx.x & 15) * 4;
    #pragma unroll
    for (int i = 0; i < 4; ++i) {
        float4 v = *(const float4*)(W + (size_t)(k0 + i * 16 + r) * N + n0 + c4);
        t[i*16 + r][c4 + 0] = v.x;
        t[i*16 + r][c4 + 1] = v.y;
        t[i*16 + r][c4 + 2] = v.z;
        t[i*16 + r][c4 + 3] = v.w;
    }
    __syncthreads();
    #pragma unroll
    for (int i = 0; i < 4; ++i) {
        ushort4 o;
        o.x = f2bf(t[c4 + 0][i*16 + r]);
        o.y = f2bf(t[c4 + 1][i*16 + r]);
        o.z = f2bf(t[c4 + 2][i*16 + r]);
        o.w = f2bf(t[c4 + 3][i*16 + r]);
        *(ushort4*)(Wt + (size_t)(n0 + i * 16 + r) * K + k0 + c4) = o;
    }
}

// W1 transpose pre-scaled by g2[k]: Wt[n][k] = bf16(g2[k] * W1[k][n])
__device__ __forceinline__ void transpose_dev_scaled(const float* __restrict__ W,
                                                     const float* __restrict__ scl,
                                                     unsigned short* __restrict__ Wt,
                                                     int K, int N, int bx, int by,
                                                     float (*t)[65]) {
    int n0 = bx * 64, k0 = by * 64;
    int r = threadIdx.x >> 4, c4 = (threadIdx.x & 15) * 4;
    #pragma unroll
    for (int i = 0; i < 4; ++i) {
        float4 v = *(const float4*)(W + (size_t)(k0 + i * 16 + r) * N + n0 + c4);
        t[i*16 + r][c4 + 0] = v.x;
        t[i*16 + r][c4 + 1] = v.y;
        t[i*16 + r][c4 + 2] = v.z;
        t[i*16 + r][c4 + 3] = v.w;
    }
    __syncthreads();
    float4 sv = *(const float4*)(scl + k0 + c4);
    #pragma unroll
    for (int i = 0; i < 4; ++i) {
        ushort4 o;
        o.x = f2bf(t[c4 + 0][i*16 + r] * sv.x);
        o.y = f2bf(t[c4 + 1][i*16 + r] * sv.y);
        o.z = f2bf(t[c4 + 2][i*16 + r] * sv.z);
        o.w = f2bf(t[c4 + 3][i*16 + r] * sv.w);
        *(ushort4*)(Wt + (size_t)(n0 + i * 16 + r) * K + k0 + c4) = o;
    }
}

// blocks: [0,576) Wq/Wk/Wv/Wo | [576,1152) W1 (g2-scaled) | [1152,1728) W2 |
//         [1728,1737) concat | [1737,1749) GEMV c2/cb | [1749,...) LN1 wave/row
__global__ __launch_bounds__(256) void prep_all(const float* __restrict__ Wq,
                                                const float* __restrict__ Wk,
                                                const float* __restrict__ Wv,
                                                const float* __restrict__ Wo,
                                                const float* __restrict__ W1,
                                                const float* __restrict__ W2,
                                                const float* __restrict__ bq,
                                                const float* __restrict__ bk,
                                                const float* __restrict__ bv,
                                                const float* __restrict__ x,
                                                const float* __restrict__ g1,
                                                const float* __restrict__ b1,
                                                const float* __restrict__ g2,
                                                const float* __restrict__ b2,
                                                const float* __restrict__ bm1,
                                                unsigned short* __restrict__ wqkvt,
                                                unsigned short* __restrict__ wot,
                                                unsigned short* __restrict__ w1t,
                                                unsigned short* __restrict__ w2t,
                                                float* __restrict__ bqkv,
                                                float* __restrict__ c2v,
                                                float* __restrict__ cbv,
                                                unsigned short* __restrict__ ln1h) {
    __shared__ float t[64][65];
    int blk = blockIdx.x;
    int tid = threadIdx.x;

    if (blk < 576) {
        int which = blk / 144, idx = blk % 144;
        const float* src = (which == 0) ? Wq : (which == 1) ? Wk : (which == 2) ? Wv : Wo;
        unsigned short* dst = (which == 3) ? wot : wqkvt + (size_t)which * C_ * C_;
        transpose_dev(src, dst, C_, C_, idx % 12, idx / 12, t);
    } else if (blk < 1152) {
        int idx = blk - 576;
        transpose_dev_scaled(W1, g2, w1t, C_, 4 * C_, idx % 48, idx / 48, t);
    } else if (blk < 1728) {
        int idx = blk - 1152;
        transpose_dev(W2, w2t, 4 * C_, C_, idx % 12, idx / 12, t);
    } else if (blk < 1737) {
        int i = (blk - 1728) * 256 + tid;   // 2304 total
        bqkv[i] = (i < 768) ? bq[i] : (i < 1536) ? bk[i - 768] : bv[i - 1536];
    } else if (blk < 1749) {
        // GEMV: c2[n] = sum_k g2[k]*W1[k][n];  cb[n] = sum_k b2[k]*W1[k][n] + bm1[n]
        int n = (blk - 1737) * 256 + tid;   // 0..3071
        float s2 = 0.f, sb = 0.f;
        for (int k = 0; k < C_; ++k) {
            float wv = W1[(size_t)k * (4 * C_) + n];
            s2 = fmaf(g2[k], wv, s2);
            sb = fmaf(b2[k], wv, sb);
        }
        c2v[n] = s2;
        cbv[n] = sb + bm1[n];
    } else {
        // LN1: wave-per-row, vectorized float4 loads, zero LDS/barriers
        int row = (blk - 1749) * 4 + (tid >> 6);
        int lane = tid & 63;
        const float* xr = x + (size_t)row * C_;
        float v[12];
        #pragma unroll
        for (int p = 0; p < 3; ++p) {
            float4 f4 = *(const float4*)(xr + p * 256 + lane * 4);
            v[p*4+0] = f4.x; v[p*4+1] = f4.y; v[p*4+2] = f4.z; v[p*4+3] = f4.w;
        }
        float s = 0.f;
        #pragma unroll
        for (int i = 0; i < 12; ++i) s += v[i];
        #pragma unroll
        for (int off = 1; off < 64; off <<= 1) s += __shfl_xor(s, off);
        float mean = s * (1.0f / C_);
        float qs = 0.f;
        #pragma unroll
        for (int i = 0; i < 12; ++i) { v[i] -= mean; qs += v[i] * v[i]; }
        #pragma unroll
        for (int off = 1; off < 64; off <<= 1) qs += __shfl_xor(qs, off);
        float rs = rsqrtf(qs * (1.0f / C_) + 1e-5f);
        unsigned short* orow = ln1h + (size_t)row * C_;
        #pragma unroll
        for (int p = 0; p < 3; ++p) {
            float4 gv = *(const float4*)(g1 + p * 256 + lane * 4);
            float4 bv = *(const float4*)(b1 + p * 256 + lane * 4);
            ushort4 o4;
            o4.x = f2bf(v[p*4+0] * rs * gv.x + bv.x);
            o4.y = f2bf(v[p*4+1] * rs * gv.y + bv.y);
            o4.z = f2bf(v[p*4+2] * rs * gv.z + bv.z);
            o4.w = f2bf(v[p*4+3] * rs * gv.w + bv.w);
            *(ushort4*)(orow + p * 256 + lane * 4) = o4;
        }
    }
}

// ---------------- LN2 stats only: per-row (mu, rs) from bf16 xmid ----------------
__global__ __launch_bounds__(256) void ln2_stats(const unsigned short* __restrict__ x,
                                                 float2* __restrict__ stats) {
    int row = blockIdx.x * 4 + (threadIdx.x >> 6);
    int lane = threadIdx.x & 63;
    const unsigned short* xr = x + (size_t)row * C_;
    float v[12];
    #pragma unroll
    for (int p = 0; p < 3; ++p) {
        ushort4 u4 = *(const ushort4*)(xr + p * 256 + lane * 4);
        v[p*4+0] = bf2f(u4.x); v[p*4+1] = bf2f(u4.y);
        v[p*4+2] = bf2f(u4.z); v[p*4+3] = bf2f(u4.w);
    }
    float s = 0.f;
    #pragma unroll
    for (int i = 0; i < 12; ++i) s += v[i];
    #pragma unroll
    for (int off = 1; off < 64; off <<= 1) s += __shfl_xor(s, off);
    float mean = s * (1.0f / C_);
    float qs = 0.f;
    #pragma unroll
    for (int i = 0; i < 12; ++i) { float d = v[i] - mean; qs += d * d; }
    #pragma unroll
    for (int off = 1; off < 64; off <<= 1) qs += __shfl_xor(qs, off);
    float rs = rsqrtf(qs * (1.0f / C_) + 1e-5f);
    if (lane == 0) stats[row] = make_float2(mean, rs);
}

// ---------------- bf16 MFMA GEMM: C = A @ Bt^T + bias ----------------
// Double-buffered LDS, prefetch-next-before-compute, 1 barrier/iter.
// 1D grid with bijective XCD-chunked remap (grid % 8 == 0 required).
// EPI: 1 = gelu -> bf16, 5 = packed qkv (V cols>=1536 -> vT),
//      6 = + bf16 resid -> fp32, 7 = + fp32 resid -> bf16,
//      8 = fused-LN2 W1: bias=cb, resid=stats(float2), aux=c2 (float); gelu -> bf16
template <int EPI>
__global__ __launch_bounds__(256) void gemm_bf16(const unsigned short* __restrict__ A,
                                                 const unsigned short* __restrict__ Bt,
                                                 const float* __restrict__ bias,
                                                 const void* __restrict__ resid,
                                                 void* __restrict__ Cout,
                                                 unsigned short* __restrict__ aux,
                                                 int M, int N, int K, int gx) {
    __shared__ short As[2][128 * 32];
    __shared__ short Bs[2][128 * 32];
    int tid = threadIdx.x;
    int w = tid >> 6, l = tid & 63;
    int nb = gridDim.x;
    int per = nb >> 3;
    int fid = (int)blockIdx.x;
    int wid = (fid & 7) * per + (fid >> 3);
    int bn = wid % gx, bm = wid / gx;
    int wr = w >> 1, wc = w & 1;

    f32x4 acc[4][4];
    #pragma unroll
    for (int m = 0; m < 4; ++m)
        #pragma unroll
        for (int n = 0; n < 4; ++n)
            acc[m][n] = (f32x4){0.f, 0.f, 0.f, 0.f};

    const short* Ag = (const short*)A + (size_t)(bm * 128) * K;
    const short* Bg = (const short*)Bt + (size_t)(bn * 128) * K;
    int srow = tid >> 2;
    int scol = (tid & 3) * 8;
    int lrow = l & 15, lk = (l >> 4) * 8;

    auto stage = [&](int buf, int k0) {
        #pragma unroll
        for (int i = 0; i < 2; ++i) {
            gl_lds16(Ag + (size_t)(i * 64 + srow) * K + k0 + scol,
                     (char*)&As[buf][0] + i * 4096 + w * 1024);
            gl_lds16(Bg + (size_t)(i * 64 + srow) * K + k0 + scol,
                     (char*)&Bs[buf][0] + i * 4096 + w * 1024);
        }
    };

    int nk = K / 32;
    stage(0, 0);
    __syncthreads();   // buf0 staged (drains vmcnt)

    for (int kt = 0; kt < nk; ++kt) {
        int cur = kt & 1;
        if (kt + 1 < nk) stage(cur ^ 1, (kt + 1) * 32);   // prefetch overlaps compute

        short8 av[4], bv[4];
        #pragma unroll
        for (int m = 0; m < 4; ++m)
            av[m] = *(const short8*)&As[cur][(wr * 64 + m * 16 + lrow) * 32 + lk];
        #pragma unroll
        for (int n = 0; n < 4; ++n)
            bv[n] = *(const short8*)&Bs[cur][(wc * 64 + n * 16 + lrow) * 32 + lk];
        #pragma unroll
        for (int m = 0; m < 4; ++m)
            #pragma unroll
            for (int n = 0; n < 4; ++n)
                acc[m][n] = __builtin_amdgcn_mfma_f32_16x16x32_bf16(av[m], bv[n], acc[m][n], 0, 0, 0);

        __syncthreads();   // reads of cur retired + prefetch DMA landed
    }

    int lcol = l & 15, lr4 = (l >> 4) * 4;
    int row0 = bm * 128 + wr * 64;
    int col0 = bn * 128 + wc * 64;

    if (EPI == 8) {
        // fused LN2: v = rs*acc + cb[col] - mu*rs*c2[col]; gelu; bf16
        const float2* st = (const float2*)resid;
        const float* c2 = (const float*)aux;
        #pragma unroll
        for (int m = 0; m < 4; ++m) {
            #pragma unroll
            for (int r = 0; r < 4; ++r) {
                int row = row0 + m * 16 + lr4 + r;
                float2 s2 = st[row];
                float murs = s2.x * s2.y;
                #pragma unroll
                for (int n = 0; n < 4; ++n) {
                    int col = col0 + n * 16 + lcol;
                    float v = fmaf(s2.y, acc[m][n][r], fmaf(-murs, c2[col], bias[col]));
                    float u = fmaf(0.044715f * v, v * v, v);
                    float e = __builtin_amdgcn_exp2f(u * -2.3022127f);
                    v = v * __builtin_amdgcn_rcpf(1.0f + e);
                    ((unsigned short*)Cout)[(size_t)row * N + col] = f2bf(v);
                }
            }
        }
        return;
    }

    #pragma unroll
    for (int m = 0; m < 4; ++m) {
        #pragma unroll
        for (int n = 0; n < 4; ++n) {
            int col = col0 + n * 16 + lcol;
            float bz = bias[col];
            if (EPI == 5 && col0 >= 1536) {
                // V half-tile: write transposed vT[b][c][t], 4 consecutive t
                ushort4 o4;
                o4.x = f2bf(acc[m][n][0] + bz);
                o4.y = f2bf(acc[m][n][1] + bz);
                o4.z = f2bf(acc[m][n][2] + bz);
                o4.w = f2bf(acc[m][n][3] + bz);
                int row = row0 + m * 16 + lr4;
                int c = col - 1536;
                *(ushort4*)(aux + ((size_t)(row >> 11) * 768 + c) * (size_t)T_ + (row & 2047)) = o4;
            } else {
                #pragma unroll
                for (int r = 0; r < 4; ++r) {
                    int row = row0 + m * 16 + lr4 + r;
                    float v = acc[m][n][r] + bz;
                    if (EPI == 1) {
                        float u = fmaf(0.044715f * v, v * v, v);
                        float e = __builtin_amdgcn_exp2f(u * -2.3022127f);
                        v = v * __builtin_amdgcn_rcpf(1.0f + e);
                        ((unsigned short*)Cout)[(size_t)row * N + col] = f2bf(v);
                    } else if (EPI == 6) {
                        v += bf2f(((const unsigned short*)resid)[(size_t)row * N + col]);
                        ((float*)Cout)[(size_t)row * N + col] = v;
                    } else if (EPI == 7) {
                        v += ((const float*)resid)[(size_t)row * N + col];
                        ((unsigned short*)Cout)[(size_t)row * N + col] = f2bf(v);
                    } else {
                        ((unsigned short*)Cout)[(size_t)row * N + col] = f2bf(v);
                    }
                }
            }
        }
    }
}

// ---------------- MFMA flash attention v9 (verified 95.5us config, verbatim) ----------
// 1536 blocks = 48 bh * 32 single 64-q tiles, heavy-first within XCD chunks.
// 4 waves x 16 q-rows. KVBLK=128. K AND V^T staged via gl_lds with pre-swizzled
// global source. V^T comes pre-transposed from the qkv GEMM epilogue (vT[b][c][t]).
// S^T = mfma(K,Q): lane-local softmax (always-exp vs running ref, 4-way tree
// partials, rare post-fix). P in regs: cvt_pk + 4-lane-group shuffles -> PV A-frags.
__global__ __launch_bounds__(256) void attn_v9(const unsigned short* __restrict__ QKV,
                                               const unsigned short* __restrict__ vT,
                                               unsigned short* __restrict__ O) {
    __shared__ short Ks[128 * 64];   // [k][d], byte ^= (k&7)<<4  (16 KB)
    __shared__ short Vt[64 * 128];   // [d][k], byte ^= (d&7)<<4  (16 KB)

    int tid = threadIdx.x;
    int w = tid >> 6, l = tid & 63;
    int g = l >> 4, lc = l & 15;
    // bijective XCD remap: 1536 = 8 * 192; consecutive wid share bh (L2 locality)
    int wid = (int)(blockIdx.x & 7) * 192 + (int)(blockIdx.x >> 3);
    int bh = wid >> 5;
    int a  = 31 - (wid & 31);        // heavy q-tiles dispatched first
    int b = bh / H_, h = bh % H_;
    const size_t bT = (size_t)b * T_;
    const unsigned short* Qp = QKV + h * D_;
    const unsigned short* Kp = QKV + 768 + h * D_;
    const unsigned short* vTb = vT + ((size_t)b * 768 + h * 64) * (size_t)T_;
    const float SCL = 0.125f * 1.44269504088896340736f;  // 1/sqrt(D) * log2(e)

    int qw = a * 64 + w * 16;        // wave's q rows: qw..qw+15

    // Q B-fragments (col q = qw+lc, k-dim = d)
    short8 qf[2];
    {
        const unsigned short* qp = Qp + (bT + qw + lc) * QS_;
        qf[0] = *(const short8*)(qp + g * 8);
        qf[1] = *(const short8*)(qp + 32 + g * 8);
    }

    f32x4 oacc[4];
    #pragma unroll
    for (int n = 0; n < 4; ++n) oacc[n] = (f32x4){0.f, 0.f, 0.f, 0.f};
    float mrun = 4.0f, lpart = 0.f;

    int ntiles = (a >> 1) + 1;
    for (int kt = 0; kt < ntiles; ++kt) {
        int k0 = kt * 128;
        if (kt) __syncthreads();     // all waves done reading Ks/Vt of prev tile

        // --- stage K [128][64] via global_load_lds, pre-swizzled source ---
        #pragma unroll
        for (int c = 0; c < 4; ++c) {
            int row = w * 32 + c * 8 + (l >> 3);
            int inner = (l & 7) * 16;
            const char* src = (const char*)(Kp + (bT + k0 + row) * QS_)
                              + (inner ^ ((row & 7) << 4));
            gl_lds16(src, (char*)Ks + w * 4096 + c * 1024);
        }
        // --- stage V^T [64][128] via global_load_lds, pre-swizzled source ---
        #pragma unroll
        for (int c = 0; c < 4; ++c) {
            int d = w * 16 + c * 4 + (l >> 4);
            int inner = (l & 15) * 16;
            const char* src = (const char*)(vTb + (size_t)d * T_ + k0)
                              + (inner ^ ((d & 7) << 4));
            gl_lds16(src, (char*)Vt + w * 4096 + c * 1024);
        }
        __syncthreads();

        // --- S^T = K @ Q^T per 16-k frag; immediate exp with mrun ref ---
        uint2 qd[8];
        float lmaxP[4] = {-INFINITY, -INFINITY, -INFINITY, -INFINITY};
        float rsumP[4] = {0.f, 0.f, 0.f, 0.f};
        bool full = (k0 + 127 <= qw);
        #pragma unroll
        for (int mk = 0; mk < 8; ++mk) {
            f32x4 s = (f32x4){0.f, 0.f, 0.f, 0.f};
            __builtin_amdgcn_s_setprio(1);
            #pragma unroll
            for (int ksd = 0; ksd < 2; ++ksd) {
                int row = mk * 16 + lc;
                int byt = (row * 128 + ksd * 64 + g * 16) ^ ((row & 7) << 4);
                short8 av = *(const short8*)((char*)Ks + byt);
                s = __builtin_amdgcn_mfma_f32_16x16x32_bf16(av, qf[ksd], s, 0, 0, 0);
            }
            __builtin_amdgcn_s_setprio(0);
            // lane holds S^T[k = k0+mk*16+g*4+r][q = qw+lc]
            float p[4];
            #pragma unroll
            for (int r = 0; r < 4; ++r) {
                float sv = s[r] * SCL;
                if (!full && (k0 + mk * 16 + g * 4 + r > qw + lc)) sv = -INFINITY;
                lmaxP[r] = fmaxf(lmaxP[r], sv);
                float pv = __builtin_amdgcn_exp2f(sv - mrun);
                p[r] = pv;
                rsumP[r] += pv;
            }
            qd[mk].x = cvt_pk_bf16(p[0], p[1]);
            qd[mk].y = cvt_pk_bf16(p[2], p[3]);
        }
        float lmax = fmaxf(fmaxf(lmaxP[0], lmaxP[1]), fmaxf(lmaxP[2], lmaxP[3]));
        lpart += (rsumP[0] + rsumP[1]) + (rsumP[2] + rsumP[3]);

        // --- PV: assemble A-frags via 4-lane-group shuffles, MFMA with Vt ---
        #pragma unroll
        for (int ks = 0; ks < 4; ++ks) {
            uint2 qa = qd[ks * 2], qb = qd[ks * 2 + 1];
            int srcLo = lc + ((g & 1) << 5);
            int srcHi = srcLo + 16;
            unsigned a0 = (unsigned)__shfl((int)qa.x, srcLo);
            unsigned a1 = (unsigned)__shfl((int)qa.y, srcLo);
            unsigned a2 = (unsigned)__shfl((int)qa.x, srcHi);
            unsigned a3 = (unsigned)__shfl((int)qa.y, srcHi);
            unsigned b0 = (unsigned)__shfl((int)qb.x, srcLo);
            unsigned b1 = (unsigned)__shfl((int)qb.y, srcLo);
            unsigned b2 = (unsigned)__shfl((int)qb.x, srcHi);
            unsigned b3 = (unsigned)__shfl((int)qb.y, srcHi);
            bool lo = (g < 2);
            union { unsigned u[4]; short8 s8; } pa;
            pa.u[0] = lo ? a0 : b0;
            pa.u[1] = lo ? a1 : b1;
            pa.u[2] = lo ? a2 : b2;
            pa.u[3] = lo ? a3 : b3;
            short8 vbv[4];
            #pragma unroll
            for (int n = 0; n < 4; ++n) {
                int row = n * 16 + lc;
                int byt = (row * 256 + ks * 64 + g * 16) ^ ((row & 7) << 4);
                vbv[n] = *(const short8*)((char*)Vt + byt);
            }
            __builtin_amdgcn_s_setprio(1);
            #pragma unroll
            for (int n = 0; n < 4; ++n)
                oacc[n] = __builtin_amdgcn_mfma_f32_16x16x32_bf16(pa.s8, vbv[n], oacc[n], 0, 0, 0);
            __builtin_amdgcn_s_setprio(0);
        }

        // --- rare violation fix: one common scale repairs oacc & lpart ---
        if (__any(lmax > mrun + 8.0f)) {
            lmax = fmaxf(lmax, __shfl_xor(lmax, 16));
            lmax = fmaxf(lmax, __shfl_xor(lmax, 32));
            float mnew = fmaxf(mrun, lmax);
            float cc = __builtin_amdgcn_exp2f(mrun - mnew);
            lpart *= cc;
            mrun = mnew;
            #pragma unroll
            for (int r = 0; r < 4; ++r) {
                float cr = __shfl(cc, (l & 48) + g * 4 + r);
                #pragma unroll
                for (int n = 0; n < 4; ++n) oacc[n][r] *= cr;
            }
        }
    }

    // --- epilogue: group-reduce l, deliver inv to oacc rows, write O ---
    float lv = lpart;
    lv += __shfl_xor(lv, 16);
    lv += __shfl_xor(lv, 32);
    float linv = 1.0f / lv;
    float inv[4];
    #pragma unroll
    for (int r = 0; r < 4; ++r) inv[r] = __shfl(linv, (l & 48) + g * 4 + r);
    #pragma unroll
    for (int n = 0; n < 4; ++n) {
        int col = h * D_ + n * 16 + lc;
        #pragma unroll
        for (int r = 0; r < 4; ++r) {
            int row = qw + g * 4 + r;
            O[(bT + row) * C_ + col] = f2bf(oacc[n][r] * inv[r]);
        }
    }
}

extern "C" void kernel_launch(void* const* d_in, const int* in_sizes, int n_in,
                              void* d_out, int out_size, void* d_ws, size_t ws_size,
                              hipStream_t stream) {
    const float* x   = (const float*)d_in[0];
    const float* Wq  = (const float*)d_in[1];
    const float* bq  = (const float*)d_in[2];
    const float* Wk  = (const float*)d_in[3];
    const float* bk  = (const float*)d_in[4];
    const float* Wv  = (const float*)d_in[5];
    const float* bv  = (const float*)d_in[6];
    const float* Wo  = (const float*)d_in[7];
    const float* bo  = (const float*)d_in[8];
    const float* g1  = (const float*)d_in[9];
    const float* b1  = (const float*)d_in[10];
    const float* g2  = (const float*)d_in[11];
    const float* b2  = (const float*)d_in[12];
    const float* W1  = (const float*)d_in[13];
    const float* bm1 = (const float*)d_in[14];
    const float* W2  = (const float*)d_in[15];
    const float* bm2 = (const float*)d_in[16];
    float* out = (float*)d_out;

    const size_t S = (size_t)B_ * T_ * C_;   // 6,291,456 elems
    char* base = (char*)d_ws;
    unsigned short* ln1h = (unsigned short*)base;
    unsigned short* qkvb = (unsigned short*)(base + 2 * S);
    unsigned short* o    = ln1h;
    float2* stats        = (float2*)(base + 2 * S);                // qkv dead after attn
    unsigned short* vT   = (unsigned short*)(base + 8 * S);        // [B][768][2048] bf16
    unsigned short* hid  = (unsigned short*)(base + 4 * S);        // written after attn
    unsigned short* xmid = (unsigned short*)(base + 12 * S);       // bf16
    unsigned short* wqkvt = (unsigned short*)(base + 16 * S);      // [2304][768]
    unsigned short* wot   = wqkvt + (size_t)3 * C_ * C_;
    unsigned short* w1t   = wot + (size_t)C_ * C_;                 // [3072][768], g2-scaled
    unsigned short* w2t   = w1t + (size_t)C_ * 4 * C_;             // [768][3072]
    float* bqkv           = (float*)(w2t + (size_t)C_ * 4 * C_);   // [2304]
    float* c2v            = bqkv + 2304;                           // [3072]
    float* cbv            = c2v + 3072;                            // [3072]

    const int M = B_ * T_;
    dim3 blk(256);

    prep_all<<<dim3(1749 + M / 4), blk, 0, stream>>>(Wq, Wk, Wv, Wo, W1, W2,
                                                     bq, bk, bv, x, g1, b1, g2, b2, bm1,
                                                     wqkvt, wot, w1t, w2t, bqkv, c2v, cbv, ln1h);

    gemm_bf16<5><<<dim3((QS_ / 128) * (M / 128)), blk, 0, stream>>>(ln1h, wqkvt, bqkv, nullptr, qkvb, vT, M, QS_, C_, QS_ / 128);

    attn_v9<<<dim3(B_ * H_ * 32), blk, 0, stream>>>(qkvb, vT, o);

    // Wo: + fp32 resid (x) -> bf16 xmid
    gemm_bf16<7><<<dim3((C_ / 128) * (M / 128)), blk, 0, stream>>>(o, wot, bo, x, xmid, nullptr, M, C_, C_, C_ / 128);
    // LN2 stats only (mu, rs per row); LN folded into W1
    ln2_stats<<<dim3(M / 4), blk, 0, stream>>>(xmid, stats);
    // W1 fused-LN2: A = raw xmid, B = g2-scaled W1^T, epilogue applies affine + gelu
    gemm_bf16<8><<<dim3((4 * C_ / 128) * (M / 128)), blk, 0, stream>>>(xmid, w1t, cbv, stats, hid, (unsigned short*)c2v, M, 4 * C_, C_, 4 * C_ / 128);
    // W2: + bf16 resid (xmid) -> fp32 out
    gemm_bf16<6><<<dim3((C_ / 128) * (M / 128)), blk, 0, stream>>>(hid, w2t, bm2, xmid, out, nullptr, M, C_, 4 * C_, C_ / 128);
}

// Round 22
// 292.226 us; speedup vs baseline: 1.1806x; 1.1806x over previous
//
#include <hip/hip_runtime.h>
#include <hip/hip_bf16.h>

#define B_ 4
#define T_ 2048
#define C_ 768
#define H_ 12
#define D_ 64
#define QS_ 2304   // packed qkv row stride

typedef __attribute__((ext_vector_type(8))) short short8;
typedef __attribute__((ext_vector_type(4))) short short4v;
typedef __attribute__((ext_vector_type(4))) float f32x4;

__device__ __forceinline__ unsigned short f2bf(float f) {
    __hip_bfloat16 h = __float2bfloat16(f);
    return *reinterpret_cast<unsigned short*>(&h);
}

__device__ __forceinline__ float bf2f(unsigned short u) {
    return __bfloat162float(*reinterpret_cast<const __hip_bfloat16*>(&u));
}

__device__ __forceinline__ unsigned cvt_pk_bf16(float lo, float hi) {
    unsigned r;
    asm("v_cvt_pk_bf16_f32 %0, %1, %2" : "=v"(r) : "v"(lo), "v"(hi));
    return r;
}

__device__ __forceinline__ void gl_lds16(const void* g, void* l) {
    __builtin_amdgcn_global_load_lds((const __attribute__((address_space(1))) unsigned int*)g,
                                     (__attribute__((address_space(3))) unsigned int*)l,
                                     16, 0, 0);
}

// ---------------- fused prep: 6 weight transposes + bias concat + LN1 (wave/row) ------
__device__ __forceinline__ void transpose_dev(const float* __restrict__ W,
                                              unsigned short* __restrict__ Wt,
                                              int K, int N, int bx, int by,
                                              float (*t)[65]) {
    int n0 = bx * 64, k0 = by * 64;
    int r = threadIdx.x >> 4, c4 = (threadIdx.x & 15) * 4;
    #pragma unroll
    for (int i = 0; i < 4; ++i) {
        float4 v = *(const float4*)(W + (size_t)(k0 + i * 16 + r) * N + n0 + c4);
        t[i*16 + r][c4 + 0] = v.x;
        t[i*16 + r][c4 + 1] = v.y;
        t[i*16 + r][c4 + 2] = v.z;
        t[i*16 + r][c4 + 3] = v.w;
    }
    __syncthreads();
    #pragma unroll
    for (int i = 0; i < 4; ++i) {
        ushort4 o;
        o.x = f2bf(t[c4 + 0][i*16 + r]);
        o.y = f2bf(t[c4 + 1][i*16 + r]);
        o.z = f2bf(t[c4 + 2][i*16 + r]);
        o.w = f2bf(t[c4 + 3][i*16 + r]);
        *(ushort4*)(Wt + (size_t)(n0 + i * 16 + r) * K + k0 + c4) = o;
    }
}

// blocks: [0,576) Wq/Wk/Wv/Wo (144 each) | [576,1152) W1 | [1152,1728) W2 |
//         [1728,1737) concat | [1737,3785) ln1: wave-per-row, 4 rows/block
__global__ __launch_bounds__(256) void prep_all(const float* __restrict__ Wq,
                                                const float* __restrict__ Wk,
                                                const float* __restrict__ Wv,
                                                const float* __restrict__ Wo,
                                                const float* __restrict__ W1,
                                                const float* __restrict__ W2,
                                                const float* __restrict__ bq,
                                                const float* __restrict__ bk,
                                                const float* __restrict__ bv,
                                                const float* __restrict__ x,
                                                const float* __restrict__ g1,
                                                const float* __restrict__ b1,
                                                unsigned short* __restrict__ wqkvt,
                                                unsigned short* __restrict__ wot,
                                                unsigned short* __restrict__ w1t,
                                                unsigned short* __restrict__ w2t,
                                                float* __restrict__ bqkv,
                                                unsigned short* __restrict__ ln1h) {
    __shared__ float t[64][65];
    int blk = blockIdx.x;
    int tid = threadIdx.x;

    if (blk < 576) {
        int which = blk / 144, idx = blk % 144;
        const float* src = (which == 0) ? Wq : (which == 1) ? Wk : (which == 2) ? Wv : Wo;
        unsigned short* dst = (which == 3) ? wot : wqkvt + (size_t)which * C_ * C_;
        transpose_dev(src, dst, C_, C_, idx % 12, idx / 12, t);
    } else if (blk < 1152) {
        int idx = blk - 576;
        transpose_dev(W1, w1t, C_, 4 * C_, idx % 48, idx / 48, t);
    } else if (blk < 1728) {
        int idx = blk - 1152;
        transpose_dev(W2, w2t, 4 * C_, C_, idx % 12, idx / 12, t);
    } else if (blk < 1737) {
        int i = (blk - 1728) * 256 + tid;   // 2304 total
        bqkv[i] = (i < 768) ? bq[i] : (i < 1536) ? bk[i - 768] : bv[i - 1536];
    } else {
        // LN1: wave-per-row, vectorized float4 loads, zero LDS/barriers
        int row = (blk - 1737) * 4 + (tid >> 6);
        int lane = tid & 63;
        const float* xr = x + (size_t)row * C_;
        float v[12];
        #pragma unroll
        for (int p = 0; p < 3; ++p) {
            float4 f4 = *(const float4*)(xr + p * 256 + lane * 4);
            v[p*4+0] = f4.x; v[p*4+1] = f4.y; v[p*4+2] = f4.z; v[p*4+3] = f4.w;
        }
        float s = 0.f;
        #pragma unroll
        for (int i = 0; i < 12; ++i) s += v[i];
        #pragma unroll
        for (int off = 1; off < 64; off <<= 1) s += __shfl_xor(s, off);
        float mean = s * (1.0f / C_);
        float qs = 0.f;
        #pragma unroll
        for (int i = 0; i < 12; ++i) { v[i] -= mean; qs += v[i] * v[i]; }
        #pragma unroll
        for (int off = 1; off < 64; off <<= 1) qs += __shfl_xor(qs, off);
        float rs = rsqrtf(qs * (1.0f / C_) + 1e-5f);
        unsigned short* orow = ln1h + (size_t)row * C_;
        #pragma unroll
        for (int p = 0; p < 3; ++p) {
            float4 gv = *(const float4*)(g1 + p * 256 + lane * 4);
            float4 bv = *(const float4*)(b1 + p * 256 + lane * 4);
            ushort4 o4;
            o4.x = f2bf(v[p*4+0] * rs * gv.x + bv.x);
            o4.y = f2bf(v[p*4+1] * rs * gv.y + bv.y);
            o4.z = f2bf(v[p*4+2] * rs * gv.z + bv.z);
            o4.w = f2bf(v[p*4+3] * rs * gv.w + bv.w);
            *(ushort4*)(orow + p * 256 + lane * 4) = o4;
        }
    }
}

// ---------------- LN2: bf16 in/out, wave-per-row, vectorized, zero barriers ----------
__global__ __launch_bounds__(256) void ln2_wave(const unsigned short* __restrict__ x,
                                                const float* __restrict__ g,
                                                const float* __restrict__ b,
                                                unsigned short* __restrict__ out) {
    int row = blockIdx.x * 4 + (threadIdx.x >> 6);
    int lane = threadIdx.x & 63;
    const unsigned short* xr = x + (size_t)row * C_;
    float v[12];
    #pragma unroll
    for (int p = 0; p < 3; ++p) {
        ushort4 u4 = *(const ushort4*)(xr + p * 256 + lane * 4);
        v[p*4+0] = bf2f(u4.x); v[p*4+1] = bf2f(u4.y);
        v[p*4+2] = bf2f(u4.z); v[p*4+3] = bf2f(u4.w);
    }
    float s = 0.f;
    #pragma unroll
    for (int i = 0; i < 12; ++i) s += v[i];
    #pragma unroll
    for (int off = 1; off < 64; off <<= 1) s += __shfl_xor(s, off);
    float mean = s * (1.0f / C_);
    float qs = 0.f;
    #pragma unroll
    for (int i = 0; i < 12; ++i) { v[i] -= mean; qs += v[i] * v[i]; }
    #pragma unroll
    for (int off = 1; off < 64; off <<= 1) qs += __shfl_xor(qs, off);
    float rs = rsqrtf(qs * (1.0f / C_) + 1e-5f);
    unsigned short* orow = out + (size_t)row * C_;
    #pragma unroll
    for (int p = 0; p < 3; ++p) {
        float4 gv = *(const float4*)(g + p * 256 + lane * 4);
        float4 bv = *(const float4*)(b + p * 256 + lane * 4);
        ushort4 o4;
        o4.x = f2bf(v[p*4+0] * rs * gv.x + bv.x);
        o4.y = f2bf(v[p*4+1] * rs * gv.y + bv.y);
        o4.z = f2bf(v[p*4+2] * rs * gv.z + bv.z);
        o4.w = f2bf(v[p*4+3] * rs * gv.w + bv.w);
        *(ushort4*)(orow + p * 256 + lane * 4) = o4;
    }
}

// ---------------- bf16 MFMA GEMM: C = A @ Bt^T + bias ----------------
// Double-buffered LDS, prefetch-next-before-compute, 1 barrier/iter.
// 1D grid with bijective XCD-chunked remap (grid % 8 == 0 required).
// EPI: 1 = gelu -> bf16 out, 5 = packed qkv (Q/K bf16; V cols>=1536 -> vT),
//      6 = + bf16 resid -> fp32 out, 7 = + fp32 resid -> bf16 out
template <int EPI>
__global__ __launch_bounds__(256) void gemm_bf16(const unsigned short* __restrict__ A,
                                                 const unsigned short* __restrict__ Bt,
                                                 const float* __restrict__ bias,
                                                 const void* __restrict__ resid,
                                                 void* __restrict__ Cout,
                                                 unsigned short* __restrict__ aux,
                                                 int M, int N, int K, int gx) {
    __shared__ short As[2][128 * 32];
    __shared__ short Bs[2][128 * 32];
    int tid = threadIdx.x;
    int w = tid >> 6, l = tid & 63;
    int nb = gridDim.x;
    int per = nb >> 3;
    int fid = (int)blockIdx.x;
    int wid = (fid & 7) * per + (fid >> 3);
    int bn = wid % gx, bm = wid / gx;
    int wr = w >> 1, wc = w & 1;

    f32x4 acc[4][4];
    #pragma unroll
    for (int m = 0; m < 4; ++m)
        #pragma unroll
        for (int n = 0; n < 4; ++n)
            acc[m][n] = (f32x4){0.f, 0.f, 0.f, 0.f};

    const short* Ag = (const short*)A + (size_t)(bm * 128) * K;
    const short* Bg = (const short*)Bt + (size_t)(bn * 128) * K;
    int srow = tid >> 2;
    int scol = (tid & 3) * 8;
    int lrow = l & 15, lk = (l >> 4) * 8;

    auto stage = [&](int buf, int k0) {
        #pragma unroll
        for (int i = 0; i < 2; ++i) {
            gl_lds16(Ag + (size_t)(i * 64 + srow) * K + k0 + scol,
                     (char*)&As[buf][0] + i * 4096 + w * 1024);
            gl_lds16(Bg + (size_t)(i * 64 + srow) * K + k0 + scol,
                     (char*)&Bs[buf][0] + i * 4096 + w * 1024);
        }
    };

    int nk = K / 32;
    stage(0, 0);
    __syncthreads();   // buf0 staged (drains vmcnt)

    for (int kt = 0; kt < nk; ++kt) {
        int cur = kt & 1;
        if (kt + 1 < nk) stage(cur ^ 1, (kt + 1) * 32);   // prefetch overlaps compute

        short8 av[4], bv[4];
        #pragma unroll
        for (int m = 0; m < 4; ++m)
            av[m] = *(const short8*)&As[cur][(wr * 64 + m * 16 + lrow) * 32 + lk];
        #pragma unroll
        for (int n = 0; n < 4; ++n)
            bv[n] = *(const short8*)&Bs[cur][(wc * 64 + n * 16 + lrow) * 32 + lk];
        #pragma unroll
        for (int m = 0; m < 4; ++m)
            #pragma unroll
            for (int n = 0; n < 4; ++n)
                acc[m][n] = __builtin_amdgcn_mfma_f32_16x16x32_bf16(av[m], bv[n], acc[m][n], 0, 0, 0);

        __syncthreads();   // reads of cur retired + prefetch DMA landed
    }

    int lcol = l & 15, lr4 = (l >> 4) * 4;
    int row0 = bm * 128 + wr * 64;
    int col0 = bn * 128 + wc * 64;
    #pragma unroll
    for (int m = 0; m < 4; ++m) {
        #pragma unroll
        for (int n = 0; n < 4; ++n) {
            int col = col0 + n * 16 + lcol;
            float bz = bias[col];
            if (EPI == 5 && col0 >= 1536) {
                // V half-tile: write transposed vT[b][c][t], 4 consecutive t
                ushort4 o4;
                o4.x = f2bf(acc[m][n][0] + bz);
                o4.y = f2bf(acc[m][n][1] + bz);
                o4.z = f2bf(acc[m][n][2] + bz);
                o4.w = f2bf(acc[m][n][3] + bz);
                int row = row0 + m * 16 + lr4;
                int c = col - 1536;
                *(ushort4*)(aux + ((size_t)(row >> 11) * 768 + c) * (size_t)T_ + (row & 2047)) = o4;
            } else {
                #pragma unroll
                for (int r = 0; r < 4; ++r) {
                    int row = row0 + m * 16 + lr4 + r;
                    float v = acc[m][n][r] + bz;
                    if (EPI == 1) {
                        float u = fmaf(0.044715f * v, v * v, v);
                        float e = __builtin_amdgcn_exp2f(u * -2.3022127f);
                        v = v * __builtin_amdgcn_rcpf(1.0f + e);
                        ((unsigned short*)Cout)[(size_t)row * N + col] = f2bf(v);
                    } else if (EPI == 6) {
                        v += bf2f(((const unsigned short*)resid)[(size_t)row * N + col]);
                        ((float*)Cout)[(size_t)row * N + col] = v;
                    } else if (EPI == 7) {
                        v += ((const float*)resid)[(size_t)row * N + col];
                        ((unsigned short*)Cout)[(size_t)row * N + col] = f2bf(v);
                    } else {
                        ((unsigned short*)Cout)[(size_t)row * N + col] = f2bf(v);
                    }
                }
            }
        }
    }
}

// ---------------- MFMA flash attention v9 (verified 95.5us config, verbatim) ----------
// 1536 blocks = 48 bh * 32 single 64-q tiles, heavy-first within XCD chunks.
// 4 waves x 16 q-rows. KVBLK=128. K AND V^T staged via gl_lds with pre-swizzled
// global source. V^T comes pre-transposed from the qkv GEMM epilogue (vT[b][c][t]).
// S^T = mfma(K,Q): lane-local softmax (always-exp vs running ref, 4-way tree
// partials, rare post-fix). P in regs: cvt_pk + 4-lane-group shuffles -> PV A-frags.
__global__ __launch_bounds__(256) void attn_v9(const unsigned short* __restrict__ QKV,
                                               const unsigned short* __restrict__ vT,
                                               unsigned short* __restrict__ O) {
    __shared__ short Ks[128 * 64];   // [k][d], byte ^= (k&7)<<4  (16 KB)
    __shared__ short Vt[64 * 128];   // [d][k], byte ^= (d&7)<<4  (16 KB)

    int tid = threadIdx.x;
    int w = tid >> 6, l = tid & 63;
    int g = l >> 4, lc = l & 15;
    // bijective XCD remap: 1536 = 8 * 192; consecutive wid share bh (L2 locality)
    int wid = (int)(blockIdx.x & 7) * 192 + (int)(blockIdx.x >> 3);
    int bh = wid >> 5;
    int a  = 31 - (wid & 31);        // heavy q-tiles dispatched first
    int b = bh / H_, h = bh % H_;
    const size_t bT = (size_t)b * T_;
    const unsigned short* Qp = QKV + h * D_;
    const unsigned short* Kp = QKV + 768 + h * D_;
    const unsigned short* vTb = vT + ((size_t)b * 768 + h * 64) * (size_t)T_;
    const float SCL = 0.125f * 1.44269504088896340736f;  // 1/sqrt(D) * log2(e)

    int qw = a * 64 + w * 16;        // wave's q rows: qw..qw+15

    // Q B-fragments (col q = qw+lc, k-dim = d)
    short8 qf[2];
    {
        const unsigned short* qp = Qp + (bT + qw + lc) * QS_;
        qf[0] = *(const short8*)(qp + g * 8);
        qf[1] = *(const short8*)(qp + 32 + g * 8);
    }

    f32x4 oacc[4];
    #pragma unroll
    for (int n = 0; n < 4; ++n) oacc[n] = (f32x4){0.f, 0.f, 0.f, 0.f};
    float mrun = 4.0f, lpart = 0.f;

    int ntiles = (a >> 1) + 1;
    for (int kt = 0; kt < ntiles; ++kt) {
        int k0 = kt * 128;
        if (kt) __syncthreads();     // all waves done reading Ks/Vt of prev tile

        // --- stage K [128][64] via global_load_lds, pre-swizzled source ---
        #pragma unroll
        for (int c = 0; c < 4; ++c) {
            int row = w * 32 + c * 8 + (l >> 3);
            int inner = (l & 7) * 16;
            const char* src = (const char*)(Kp + (bT + k0 + row) * QS_)
                              + (inner ^ ((row & 7) << 4));
            gl_lds16(src, (char*)Ks + w * 4096 + c * 1024);
        }
        // --- stage V^T [64][128] via global_load_lds, pre-swizzled source ---
        #pragma unroll
        for (int c = 0; c < 4; ++c) {
            int d = w * 16 + c * 4 + (l >> 4);
            int inner = (l & 15) * 16;
            const char* src = (const char*)(vTb + (size_t)d * T_ + k0)
                              + (inner ^ ((d & 7) << 4));
            gl_lds16(src, (char*)Vt + w * 4096 + c * 1024);
        }
        __syncthreads();

        // --- S^T = K @ Q^T per 16-k frag; immediate exp with mrun ref ---
        uint2 qd[8];
        float lmaxP[4] = {-INFINITY, -INFINITY, -INFINITY, -INFINITY};
        float rsumP[4] = {0.f, 0.f, 0.f, 0.f};
        bool full = (k0 + 127 <= qw);
        #pragma unroll
        for (int mk = 0; mk < 8; ++mk) {
            f32x4 s = (f32x4){0.f, 0.f, 0.f, 0.f};
            __builtin_amdgcn_s_setprio(1);
            #pragma unroll
            for (int ksd = 0; ksd < 2; ++ksd) {
                int row = mk * 16 + lc;
                int byt = (row * 128 + ksd * 64 + g * 16) ^ ((row & 7) << 4);
                short8 av = *(const short8*)((char*)Ks + byt);
                s = __builtin_amdgcn_mfma_f32_16x16x32_bf16(av, qf[ksd], s, 0, 0, 0);
            }
            __builtin_amdgcn_s_setprio(0);
            // lane holds S^T[k = k0+mk*16+g*4+r][q = qw+lc]
            float p[4];
            #pragma unroll
            for (int r = 0; r < 4; ++r) {
                float sv = s[r] * SCL;
                if (!full && (k0 + mk * 16 + g * 4 + r > qw + lc)) sv = -INFINITY;
                lmaxP[r] = fmaxf(lmaxP[r], sv);
                float pv = __builtin_amdgcn_exp2f(sv - mrun);
                p[r] = pv;
                rsumP[r] += pv;
            }
            qd[mk].x = cvt_pk_bf16(p[0], p[1]);
            qd[mk].y = cvt_pk_bf16(p[2], p[3]);
        }
        float lmax = fmaxf(fmaxf(lmaxP[0], lmaxP[1]), fmaxf(lmaxP[2], lmaxP[3]));
        lpart += (rsumP[0] + rsumP[1]) + (rsumP[2] + rsumP[3]);

        // --- PV: assemble A-frags via 4-lane-group shuffles, MFMA with Vt ---
        #pragma unroll
        for (int ks = 0; ks < 4; ++ks) {
            uint2 qa = qd[ks * 2], qb = qd[ks * 2 + 1];
            int srcLo = lc + ((g & 1) << 5);
            int srcHi = srcLo + 16;
            unsigned a0 = (unsigned)__shfl((int)qa.x, srcLo);
            unsigned a1 = (unsigned)__shfl((int)qa.y, srcLo);
            unsigned a2 = (unsigned)__shfl((int)qa.x, srcHi);
            unsigned a3 = (unsigned)__shfl((int)qa.y, srcHi);
            unsigned b0 = (unsigned)__shfl((int)qb.x, srcLo);
            unsigned b1 = (unsigned)__shfl((int)qb.y, srcLo);
            unsigned b2 = (unsigned)__shfl((int)qb.x, srcHi);
            unsigned b3 = (unsigned)__shfl((int)qb.y, srcHi);
            bool lo = (g < 2);
            union { unsigned u[4]; short8 s8; } pa;
            pa.u[0] = lo ? a0 : b0;
            pa.u[1] = lo ? a1 : b1;
            pa.u[2] = lo ? a2 : b2;
            pa.u[3] = lo ? a3 : b3;
            short8 vbv[4];
            #pragma unroll
            for (int n = 0; n < 4; ++n) {
                int row = n * 16 + lc;
                int byt = (row * 256 + ks * 64 + g * 16) ^ ((row & 7) << 4);
                vbv[n] = *(const short8*)((char*)Vt + byt);
            }
            __builtin_amdgcn_s_setprio(1);
            #pragma unroll
            for (int n = 0; n < 4; ++n)
                oacc[n] = __builtin_amdgcn_mfma_f32_16x16x32_bf16(pa.s8, vbv[n], oacc[n], 0, 0, 0);
            __builtin_amdgcn_s_setprio(0);
        }

        // --- rare violation fix: one common scale repairs oacc & lpart ---
        if (__any(lmax > mrun + 8.0f)) {
            lmax = fmaxf(lmax, __shfl_xor(lmax, 16));
            lmax = fmaxf(lmax, __shfl_xor(lmax, 32));
            float mnew = fmaxf(mrun, lmax);
            float cc = __builtin_amdgcn_exp2f(mrun - mnew);
            lpart *= cc;
            mrun = mnew;
            #pragma unroll
            for (int r = 0; r < 4; ++r) {
                float cr = __shfl(cc, (l & 48) + g * 4 + r);
                #pragma unroll
                for (int n = 0; n < 4; ++n) oacc[n][r] *= cr;
            }
        }
    }

    // --- epilogue: group-reduce l, deliver inv to oacc rows, write O ---
    float lv = lpart;
    lv += __shfl_xor(lv, 16);
    lv += __shfl_xor(lv, 32);
    float linv = 1.0f / lv;
    float inv[4];
    #pragma unroll
    for (int r = 0; r < 4; ++r) inv[r] = __shfl(linv, (l & 48) + g * 4 + r);
    #pragma unroll
    for (int n = 0; n < 4; ++n) {
        int col = h * D_ + n * 16 + lc;
        #pragma unroll
        for (int r = 0; r < 4; ++r) {
            int row = qw + g * 4 + r;
            O[(bT + row) * C_ + col] = f2bf(oacc[n][r] * inv[r]);
        }
    }
}

extern "C" void kernel_launch(void* const* d_in, const int* in_sizes, int n_in,
                              void* d_out, int out_size, void* d_ws, size_t ws_size,
                              hipStream_t stream) {
    const float* x   = (const float*)d_in[0];
    const float* Wq  = (const float*)d_in[1];
    const float* bq  = (const float*)d_in[2];
    const float* Wk  = (const float*)d_in[3];
    const float* bk  = (const float*)d_in[4];
    const float* Wv  = (const float*)d_in[5];
    const float* bv  = (const float*)d_in[6];
    const float* Wo  = (const float*)d_in[7];
    const float* bo  = (const float*)d_in[8];
    const float* g1  = (const float*)d_in[9];
    const float* b1  = (const float*)d_in[10];
    const float* g2  = (const float*)d_in[11];
    const float* b2  = (const float*)d_in[12];
    const float* W1  = (const float*)d_in[13];
    const float* bm1 = (const float*)d_in[14];
    const float* W2  = (const float*)d_in[15];
    const float* bm2 = (const float*)d_in[16];
    float* out = (float*)d_out;

    const size_t S = (size_t)B_ * T_ * C_;   // 6,291,456 elems
    char* base = (char*)d_ws;
    unsigned short* ln1h = (unsigned short*)base;
    unsigned short* qkvb = (unsigned short*)(base + 2 * S);
    unsigned short* o    = ln1h;
    unsigned short* ln2h = qkvb;
    unsigned short* vT   = (unsigned short*)(base + 8 * S);        // [B][768][2048] bf16
    unsigned short* hid  = (unsigned short*)(base + 4 * S);        // written after attn
    unsigned short* xmid = (unsigned short*)(base + 12 * S);       // bf16
    unsigned short* wqkvt = (unsigned short*)(base + 16 * S);      // [2304][768]
    unsigned short* wot   = wqkvt + (size_t)3 * C_ * C_;
    unsigned short* w1t   = wot + (size_t)C_ * C_;                 // [3072][768]
    unsigned short* w2t   = w1t + (size_t)C_ * 4 * C_;             // [768][3072]
    float* bqkv           = (float*)(w2t + (size_t)C_ * 4 * C_);   // [2304]

    const int M = B_ * T_;
    dim3 blk(256);

    prep_all<<<dim3(1737 + M / 4), blk, 0, stream>>>(Wq, Wk, Wv, Wo, W1, W2,
                                                     bq, bk, bv, x, g1, b1,
                                                     wqkvt, wot, w1t, w2t, bqkv, ln1h);

    gemm_bf16<5><<<dim3((QS_ / 128) * (M / 128)), blk, 0, stream>>>(ln1h, wqkvt, bqkv, nullptr, qkvb, vT, M, QS_, C_, QS_ / 128);

    attn_v9<<<dim3(B_ * H_ * 32), blk, 0, stream>>>(qkvb, vT, o);

    // Wo: + fp32 resid (x) -> bf16 xmid
    gemm_bf16<7><<<dim3((C_ / 128) * (M / 128)), blk, 0, stream>>>(o, wot, bo, x, xmid, nullptr, M, C_, C_, C_ / 128);
    ln2_wave<<<dim3(M / 4), blk, 0, stream>>>(xmid, g2, b2, ln2h);
    gemm_bf16<1><<<dim3((4 * C_ / 128) * (M / 128)), blk, 0, stream>>>(ln2h, w1t, bm1, nullptr, hid, nullptr, M, 4 * C_, C_, 4 * C_ / 128);
    // W2: + bf16 resid (xmid) -> fp32 out
    gemm_bf16<6><<<dim3((C_ / 128) * (M / 128)), blk, 0, stream>>>(hid, w2t, bm2, xmid, out, nullptr, M, C_, 4 * C_, C_ / 128);
}